// Round 3
// baseline (27.792 us; speedup 1.0000x reference)
//
#include <hip/hip_runtime.h>
#include <hip/hip_bf16.h>

typedef __attribute__((ext_vector_type(8))) short short8;
typedef __attribute__((ext_vector_type(4))) float f32x4;

#define NROW 8    // rows per block

// bf16 truncation (round-toward-zero). Safe: s = ||z3||^2 cancels exactly in
// out = s*d / max(s*sqrt(n1*n2), eps); only d,n1,n2 (pure f32) reach out.
__device__ __forceinline__ unsigned int bfhi(float f) {
    return __builtin_bit_cast(unsigned int, f);
}
__device__ __forceinline__ unsigned int pack2(float lo, float hi) {
    return (bfhi(lo) >> 16) | (bfhi(hi) & 0xffff0000u);
}

// K0: convert W1 (128x768), W2 (64x128), W3 (32x64) f32 -> bf16 in ws.
// ushort layout: W1b @ 0 (98304), W2b @ 98304 (8192), W3b @ 106496 (2048).
__global__ __launch_bounds__(256) void cvt_weights(
    const float* __restrict__ W1, const float* __restrict__ W2,
    const float* __restrict__ W3, unsigned short* __restrict__ wsb)
{
    int i = blockIdx.x * 256 + threadIdx.x;
    if (i < 98304)        wsb[i] = (unsigned short)(bfhi(W1[i]) >> 16);
    else if (i < 106496)  wsb[i] = (unsigned short)(bfhi(W2[i - 98304]) >> 16);
    else if (i < 108544)  wsb[i] = (unsigned short)(bfhi(W3[i - 106496]) >> 16);
}

// K1: fused. 512 blocks x 512 threads (8 waves), 8 rows/block -> 2 blocks/CU,
// 16 waves/CU. Phase 1: wave w streams row w (q->LDS bf16, dot/norms of p1,p2).
// Phase 2-4: 3-layer MLP via MFMA (M-tile rows 8..15 are garbage-but-safe:
// MFMA output rows are independent, garbage never contaminates rows 0..7).
__global__ __launch_bounds__(512, 4) void fused_qwn(
    const float* __restrict__ X,
    const unsigned short* __restrict__ wsb,
    const float* __restrict__ b1,
    const float* __restrict__ b2,
    const float* __restrict__ b3,
    float* __restrict__ out)
{
    __shared__ __align__(16) unsigned short xq[16][776];     // rows 8..15 never written (garbage ok)
    __shared__ __align__(16) unsigned short z1_lds[16][136];
    __shared__ __align__(16) unsigned short z2_lds[16][72];
    __shared__ float s_lds[2][16];
    __shared__ float d_lds[NROW], n1_lds[NROW], n2_lds[NROW];

    const int tid  = threadIdx.x;
    const int wid  = tid >> 6;
    const int lane = tid & 63;
    const int l15  = lane & 15;
    const int l4   = lane >> 4;
    const int row0 = blockIdx.x * NROW;

    const unsigned short* W1b = wsb;
    const unsigned short* W2b = wsb + 98304;
    const unsigned short* W3b = wsb + 106496;

    // ---------------- Phase 1: wave w streams row w ----------------
    {
        const float4* base = (const float4*)(X + (size_t)(row0 + wid) * 2304);
        float4 q[3], pa[3], pb[3];
#pragma unroll
        for (int m = 0; m < 3; ++m) q[m]  = base[lane + 64 * m];         // Xq
#pragma unroll
        for (int m = 0; m < 3; ++m) pa[m] = base[192 + lane + 64 * m];   // Xp1
#pragma unroll
        for (int m = 0; m < 3; ++m) pb[m] = base[384 + lane + 64 * m];   // Xp2

#pragma unroll
        for (int m = 0; m < 3; ++m) {
            uint2 qb;
            qb.x = pack2(q[m].x, q[m].y);
            qb.y = pack2(q[m].z, q[m].w);
            *(uint2*)&xq[wid][4 * (lane + 64 * m)] = qb;
        }
        float dd = 0.f, aa = 0.f, bb = 0.f;
#pragma unroll
        for (int m = 0; m < 3; ++m) {
            float4 x = pa[m], y = pb[m];
            dd += x.x * y.x + x.y * y.y + x.z * y.z + x.w * y.w;
            aa += x.x * x.x + x.y * x.y + x.z * x.z + x.w * x.w;
            bb += y.x * y.x + y.y * y.y + y.z * y.z + y.w * y.w;
        }
#pragma unroll
        for (int m = 1; m < 64; m <<= 1) {
            dd += __shfl_xor(dd, m);
            aa += __shfl_xor(aa, m);
            bb += __shfl_xor(bb, m);
        }
        if (lane == 0) {
            d_lds[wid]  = dd;
            n1_lds[wid] = aa;
            n2_lds[wid] = bb;
        }
    }
    __syncthreads();

    // ---------------- Phase 2: z1 = relu(Xq @ W1^T + b1), wave w: cols 16w..16w+15 ----------------
    {
        f32x4 acc = {0.f, 0.f, 0.f, 0.f};
        const unsigned short* ap = &xq[l15][l4 * 8];
        const unsigned short* bp = W1b + (size_t)(16 * wid + l15) * 768 + l4 * 8;
#pragma unroll 6
        for (int k0 = 0; k0 < 768; k0 += 32) {
            short8 a = *(const short8*)(ap + k0);
            short8 b = *(const short8*)(bp + k0);
            acc = __builtin_amdgcn_mfma_f32_16x16x32_bf16(a, b, acc, 0, 0, 0);
        }
        float bb = b1[16 * wid + l15];
#pragma unroll
        for (int r = 0; r < 4; ++r) {
            float v = fmaxf(acc[r] + bb, 0.f);
            z1_lds[4 * l4 + r][16 * wid + l15] = (unsigned short)(bfhi(v) >> 16);
        }
    }
    __syncthreads();

    // ---------------- Phase 3: z2 = relu(z1 @ W2^T + b2), waves 0-3 ----------------
    if (wid < 4) {
        f32x4 acc = {0.f, 0.f, 0.f, 0.f};
        const unsigned short* bp = W2b + (16 * wid + l15) * 128 + l4 * 8;
#pragma unroll
        for (int ks = 0; ks < 4; ++ks) {
            short8 a = *(const short8*)&z1_lds[l15][ks * 32 + l4 * 8];
            short8 b = *(const short8*)(bp + ks * 32);
            acc = __builtin_amdgcn_mfma_f32_16x16x32_bf16(a, b, acc, 0, 0, 0);
        }
        float bb = b2[16 * wid + l15];
#pragma unroll
        for (int r = 0; r < 4; ++r) {
            float v = fmaxf(acc[r] + bb, 0.f);
            z2_lds[4 * l4 + r][16 * wid + l15] = (unsigned short)(bfhi(v) >> 16);
        }
    }
    __syncthreads();

    // ---------------- Phase 4: z3 = relu(z2 @ W3^T + b3), waves 0-1; s = ||z3||^2 ----------------
    if (wid < 2) {
        f32x4 acc = {0.f, 0.f, 0.f, 0.f};
        const unsigned short* bp = W3b + (16 * wid + l15) * 64 + l4 * 8;
#pragma unroll
        for (int ks = 0; ks < 2; ++ks) {
            short8 a = *(const short8*)&z2_lds[l15][ks * 32 + l4 * 8];
            short8 b = *(const short8*)(bp + ks * 32);
            acc = __builtin_amdgcn_mfma_f32_16x16x32_bf16(a, b, acc, 0, 0, 0);
        }
        float bb = b3[16 * wid + l15];
        float sv[4];
#pragma unroll
        for (int r = 0; r < 4; ++r) {
            float v = fmaxf(acc[r] + bb, 0.f);
            sv[r] = v * v;
        }
#pragma unroll
        for (int m = 1; m < 16; m <<= 1) {
#pragma unroll
            for (int r = 0; r < 4; ++r) sv[r] += __shfl_xor(sv[r], m);
        }
        if (l15 == 0) {
#pragma unroll
            for (int r = 0; r < 4; ++r) s_lds[wid][4 * l4 + r] = sv[r];
        }
    }
    __syncthreads();

    // ---------------- Combine ----------------
    if (tid < NROW) {
        float s   = s_lds[0][tid] + s_lds[1][tid];
        float den = fmaxf(s * sqrtf(n1_lds[tid] * n2_lds[tid]), 1e-8f);
        out[row0 + tid] = (s * d_lds[tid]) / den;
    }
}

extern "C" void kernel_launch(void* const* d_in, const int* in_sizes, int n_in,
                              void* d_out, int out_size, void* d_ws, size_t ws_size,
                              hipStream_t stream)
{
    (void)in_sizes; (void)n_in; (void)out_size; (void)ws_size;
    const float* X  = (const float*)d_in[0];
    const float* W1 = (const float*)d_in[1];
    const float* b1 = (const float*)d_in[2];
    const float* W2 = (const float*)d_in[3];
    const float* b2 = (const float*)d_in[4];
    const float* W3 = (const float*)d_in[5];
    const float* b3 = (const float*)d_in[6];
    unsigned short* wsb = (unsigned short*)d_ws;

    cvt_weights<<<dim3(424), dim3(256), 0, stream>>>(W1, W2, W3, wsb);
    fused_qwn<<<dim3(512), dim3(512), 0, stream>>>(X, wsb, b1, b2, b3, (float*)d_out);
}